// Round 3
// baseline (24.404 us; speedup 1.0000x reference)
//
#include <hip/hip_runtime.h>
#include <hip/hip_bf16.h>

typedef _Float16 f16x8 __attribute__((ext_vector_type(8)));
typedef __fp16  fp16x2 __attribute__((ext_vector_type(2)));
typedef float f32x4 __attribute__((ext_vector_type(4)));

#define IN_F 128
#define OUT_F 16
#define NB 16
// K = IN_F*NB = 2048. K-step = 32 (one mfma). K-step ks: half h = ks&1, p = ks>>1.
//   lane slot s = 8*g + j (g = lane>>4) -> feature f = 4*p + g, basis n = 8*h + j.
// Within a K-step each lane group holds ONE feature; n-half is wave-uniform, so a
// K-pair (2p,2p+1) costs one Chebyshev recurrence per lane per row.

// prep: w [16][128][16] f32 -> f16 B-fragments. READ-coalesced (thread q reads w[q]);
// the 2B scatter-writes combine in L2.  wf[(ks*64+l)*8+j] = w[o][4p+g][8h+j], l=g*16+o.
__global__ void prep_w_kernel(const float* __restrict__ w, _Float16* __restrict__ wf) {
    int q = blockIdx.x * 256 + threadIdx.x;   // 0..32767
    int n = q & 15;
    int f = (q >> 4) & 127;
    int o = q >> 11;
    int p = f >> 2, g = f & 3, h = n >> 3, j = n & 7;
    int ks = 2 * p + h;
    int l = g * 16 + o;
    wf[(ks * 64 + l) * 8 + j] = (_Float16)w[q];
}

__device__ __forceinline__ void cheb_frags(float xv, f16x8& ae, f16x8& ao) {
    float x2 = xv + xv;
    float t2  = __builtin_fmaf(x2, xv,  -1.0f);
    float t3  = __builtin_fmaf(x2, t2,  -xv);
    float t4  = __builtin_fmaf(x2, t3,  -t2);
    float t5  = __builtin_fmaf(x2, t4,  -t3);
    float t6  = __builtin_fmaf(x2, t5,  -t4);
    float t7  = __builtin_fmaf(x2, t6,  -t5);
    float t8  = __builtin_fmaf(x2, t7,  -t6);
    float t9  = __builtin_fmaf(x2, t8,  -t7);
    float t10 = __builtin_fmaf(x2, t9,  -t8);
    float t11 = __builtin_fmaf(x2, t10, -t9);
    float t12 = __builtin_fmaf(x2, t11, -t10);
    float t13 = __builtin_fmaf(x2, t12, -t11);
    float t14 = __builtin_fmaf(x2, t13, -t12);
    float t15 = __builtin_fmaf(x2, t14, -t13);
    union { f16x8 v; fp16x2 h[4]; } e, od;
    e.h[0]  = __builtin_amdgcn_cvt_pkrtz(1.0f, xv);
    e.h[1]  = __builtin_amdgcn_cvt_pkrtz(t2,  t3);
    e.h[2]  = __builtin_amdgcn_cvt_pkrtz(t4,  t5);
    e.h[3]  = __builtin_amdgcn_cvt_pkrtz(t6,  t7);
    od.h[0] = __builtin_amdgcn_cvt_pkrtz(t8,  t9);
    od.h[1] = __builtin_amdgcn_cvt_pkrtz(t10, t11);
    od.h[2] = __builtin_amdgcn_cvt_pkrtz(t12, t13);
    od.h[3] = __builtin_amdgcn_cvt_pkrtz(t14, t15);
    ae = e.v;
    ao = od.v;
}

// K-split x2: block = (row-tile bid>>1, k-half bid&1). 4 waves x 32 rows = 128 rows,
// 64 features per block. xs = 32KB -> 4 blocks/CU resident (grid 1024 = 4/CU),
// 16 waves/CU = 4 waves/SIMD. Partials atomicAdd'ed into zeroed out (2 commutative
// f32 adds onto 0.0 -> bitwise order-independent).
__global__ __launch_bounds__(256) void cheb_main(const float* __restrict__ x,
                                                 const _Float16* __restrict__ wf,
                                                 float* __restrict__ out) {
    __shared__ float xs[128 * 64];             // 32 KB, XOR-swizzled float4 columns
    const int tid = threadIdx.x;
    const int bid = blockIdx.x;
    const int kh = bid & 1;                    // feature half: cols kh*64 .. +63
    const long row0 = (long)(bid >> 1) * 128;

    // stage 128 rows x 64 cols, coalesced float4; dst float4-col = c ^ (r&7)
    const float4* xg = (const float4*)(x + row0 * IN_F);
    #pragma unroll
    for (int it = 0; it < 8; ++it) {
        int idx = it * 256 + tid;              // 0..2047 float4
        int r = idx >> 4;                      // 16 float4 per row
        int c = idx & 15;
        float4 v = xg[r * 32 + kh * 16 + c];
        *(float4*)&xs[r * 64 + ((c ^ (r & 7)) << 2)] = v;
    }
    __syncthreads();

    const int l  = tid & 63;
    const int wv = tid >> 6;
    const int g  = l >> 4;                     // lane group -> feature offset
    const int o  = l & 15;                     // output column
    const int lm = l & 15;                     // A-row within tile
    const int sw = l & 7;                      // row swizzle key (r0&7 == r1&7 == l&7)

    const int r0 = wv * 32 + lm;
    const int r1 = r0 + 16;

    f32x4 acc0 = {0.f, 0.f, 0.f, 0.f};
    f32x4 acc1 = {0.f, 0.f, 0.f, 0.f};

    const f16x8* wfv = (const f16x8*)wf;

    #pragma unroll 4
    for (int p = 0; p < 16; ++p) {
        int pg = kh * 16 + p;                  // global K-pair index
        f16x8 b0 = wfv[(2 * pg) * 64 + l];     // K-step 2pg   (T0..7 half)
        f16x8 b1 = wfv[(2 * pg) * 64 + 64 + l];// K-step 2pg+1 (T8..15 half)
        int col = (((p ^ sw) & 15) << 2) | g;  // swizzled local col of f = 4p+g
        float x0 = xs[r0 * 64 + col];
        float x1 = xs[r1 * 64 + col];
        f16x8 a0e, a0o, a1e, a1o;
        cheb_frags(x0, a0e, a0o);
        cheb_frags(x1, a1e, a1o);
        acc0 = __builtin_amdgcn_mfma_f32_16x16x32_f16(a0e, b0, acc0, 0, 0, 0);
        acc0 = __builtin_amdgcn_mfma_f32_16x16x32_f16(a0o, b1, acc0, 0, 0, 0);
        acc1 = __builtin_amdgcn_mfma_f32_16x16x32_f16(a1e, b0, acc1, 0, 0, 0);
        acc1 = __builtin_amdgcn_mfma_f32_16x16x32_f16(a1o, b1, acc1, 0, 0, 0);
    }

    // C/D layout: col = lane&15 (=o), row = 4*(lane>>4) + reg
    float* op = out + (row0 + wv * 32 + 4 * g) * OUT_F + o;
    #pragma unroll
    for (int rr = 0; rr < 4; ++rr) {
        atomicAdd(&op[rr * OUT_F], acc0[rr]);
        atomicAdd(&op[(16 + rr) * OUT_F], acc1[rr]);
    }
}

extern "C" void kernel_launch(void* const* d_in, const int* in_sizes, int n_in,
                              void* d_out, int out_size, void* d_ws, size_t ws_size,
                              hipStream_t stream) {
    const float* x = (const float*)d_in[0];
    const float* w = (const float*)d_in[1];
    float* out = (float*)d_out;
    _Float16* wf = (_Float16*)d_ws;            // 64 KB of scratch

    prep_w_kernel<<<128, 256, 0, stream>>>(w, wf);
    hipMemsetAsync(out, 0, (size_t)out_size * sizeof(float), stream);
    cheb_main<<<1024, 256, 0, stream>>>(x, wf, out);
}

// Round 4
// 19.697 us; speedup vs baseline: 1.2390x; 1.2390x over previous
//
#include <hip/hip_runtime.h>
#include <hip/hip_bf16.h>

typedef _Float16 f16x8 __attribute__((ext_vector_type(8)));
typedef __fp16  fp16x2 __attribute__((ext_vector_type(2)));
typedef float f32x4 __attribute__((ext_vector_type(4)));

#define IN_F 128
#define OUT_F 16
#define NB 16
// K = 2048 = 64 K-steps of 32. K-step ks = 8P + 2q + h  (P=0..7 super, q=0..3, h=0..1).
// Lane l: g = l>>4, o = l&15, row-lane lm = l&15.
// A-frag slot j (0..7) of lane l at K-step ks holds T_{8h+j}(x[row][f]), f = 16P + 4g + q.
// => per super-iteration P a lane needs x cols 16P+4g .. 16P+4g+3 of its row: ONE float4,
//    and the wave's 64 float4 addresses = 16 complete 64B lines (perfectly coalesced).
// No LDS anywhere.

// prep: w [16][128][16] f32 -> f16 B-fragments in matching order. Read-coalesced.
// wf[(ks*64 + l)*8 + j] = w[o][16P+4g+q][8h+j]
__global__ void prep_w_kernel(const float* __restrict__ w, _Float16* __restrict__ wf) {
    int qi = blockIdx.x * 256 + threadIdx.x;  // 0..32767
    int n = qi & 15;
    int f = (qi >> 4) & 127;
    int o = qi >> 11;
    int P = f >> 4, rem = f & 15, g = rem >> 2, q = rem & 3;
    int h = n >> 3, j = n & 7;
    int ks = 8 * P + 2 * q + h;
    int l = g * 16 + o;
    wf[(ks * 64 + l) * 8 + j] = (_Float16)w[qi];
}

__device__ __forceinline__ void cheb_frags(float xv, f16x8& ae, f16x8& ao) {
    float x2 = xv + xv;
    float t2  = __builtin_fmaf(x2, xv,  -1.0f);
    float t3  = __builtin_fmaf(x2, t2,  -xv);
    float t4  = __builtin_fmaf(x2, t3,  -t2);
    float t5  = __builtin_fmaf(x2, t4,  -t3);
    float t6  = __builtin_fmaf(x2, t5,  -t4);
    float t7  = __builtin_fmaf(x2, t6,  -t5);
    float t8  = __builtin_fmaf(x2, t7,  -t6);
    float t9  = __builtin_fmaf(x2, t8,  -t7);
    float t10 = __builtin_fmaf(x2, t9,  -t8);
    float t11 = __builtin_fmaf(x2, t10, -t9);
    float t12 = __builtin_fmaf(x2, t11, -t10);
    float t13 = __builtin_fmaf(x2, t12, -t11);
    float t14 = __builtin_fmaf(x2, t13, -t12);
    float t15 = __builtin_fmaf(x2, t14, -t13);
    union { f16x8 v; fp16x2 h[4]; } e, od;
    e.h[0]  = __builtin_amdgcn_cvt_pkrtz(1.0f, xv);
    e.h[1]  = __builtin_amdgcn_cvt_pkrtz(t2,  t3);
    e.h[2]  = __builtin_amdgcn_cvt_pkrtz(t4,  t5);
    e.h[3]  = __builtin_amdgcn_cvt_pkrtz(t6,  t7);
    od.h[0] = __builtin_amdgcn_cvt_pkrtz(t8,  t9);
    od.h[1] = __builtin_amdgcn_cvt_pkrtz(t10, t11);
    od.h[2] = __builtin_amdgcn_cvt_pkrtz(t12, t13);
    od.h[3] = __builtin_amdgcn_cvt_pkrtz(t14, t15);
    ae = e.v;
    ao = od.v;
}

// block = 256 threads = 4 waves; wave = 32 rows (2 MFMA row-tiles sharing B-frags);
// grid = 512. No LDS, no barrier; ILP from 8 independent cheb chains per super-iter.
__global__ __launch_bounds__(256) void cheb_main(const float* __restrict__ x,
                                                 const _Float16* __restrict__ wf,
                                                 float* __restrict__ out) {
    const int tid = threadIdx.x;
    const long row0 = (long)blockIdx.x * 128;

    const int l  = tid & 63;
    const int wv = tid >> 6;
    const int g  = l >> 4;
    const int o  = l & 15;
    const int lm = l & 15;

    const long r0 = row0 + wv * 32 + lm;
    const long r1 = r0 + 16;

    const f32x4* x4 = (const f32x4*)x;         // 32 float4 per row
    const f16x8* wfv = (const f16x8*)wf;

    f32x4 acc0 = {0.f, 0.f, 0.f, 0.f};
    f32x4 acc1 = {0.f, 0.f, 0.f, 0.f};

    #pragma unroll
    for (int P = 0; P < 8; ++P) {
        f32x4 xv0 = x4[r0 * 32 + P * 4 + g];
        f32x4 xv1 = x4[r1 * 32 + P * 4 + g];
        #pragma unroll
        for (int q = 0; q < 4; ++q) {
            int ks = 8 * P + 2 * q;
            f16x8 b0 = wfv[ks * 64 + l];
            f16x8 b1 = wfv[ks * 64 + 64 + l];
            f16x8 a0e, a0o, a1e, a1o;
            cheb_frags(xv0[q], a0e, a0o);
            cheb_frags(xv1[q], a1e, a1o);
            acc0 = __builtin_amdgcn_mfma_f32_16x16x32_f16(a0e, b0, acc0, 0, 0, 0);
            acc0 = __builtin_amdgcn_mfma_f32_16x16x32_f16(a0o, b1, acc0, 0, 0, 0);
            acc1 = __builtin_amdgcn_mfma_f32_16x16x32_f16(a1e, b0, acc1, 0, 0, 0);
            acc1 = __builtin_amdgcn_mfma_f32_16x16x32_f16(a1o, b1, acc1, 0, 0, 0);
        }
    }

    // C/D layout: col = lane&15 (=o), row = 4*(lane>>4) + reg
    float* op = out + (row0 + wv * 32 + 4 * g) * OUT_F + o;
    #pragma unroll
    for (int rr = 0; rr < 4; ++rr) {
        op[rr * OUT_F] = acc0[rr];
        op[(16 + rr) * OUT_F] = acc1[rr];
    }
}

extern "C" void kernel_launch(void* const* d_in, const int* in_sizes, int n_in,
                              void* d_out, int out_size, void* d_ws, size_t ws_size,
                              hipStream_t stream) {
    const float* x = (const float*)d_in[0];
    const float* w = (const float*)d_in[1];
    float* out = (float*)d_out;
    _Float16* wf = (_Float16*)d_ws;            // 64 KB of scratch

    prep_w_kernel<<<128, 256, 0, stream>>>(w, wf);
    cheb_main<<<512, 256, 0, stream>>>(x, wf, out);
}

// Round 5
// 17.878 us; speedup vs baseline: 1.3650x; 1.1018x over previous
//
#include <hip/hip_runtime.h>
#include <hip/hip_bf16.h>

typedef _Float16 f16x8 __attribute__((ext_vector_type(8)));
typedef __fp16  fp16x2 __attribute__((ext_vector_type(2)));
typedef float f32x4 __attribute__((ext_vector_type(4)));

#define IN_F 128
#define OUT_F 16
#define NB 16
// K = 2048 = 64 K-steps of 32. K-step ks = 8P + 2q + h (P=0..7, q=0..3, h=0..1).
// Lane l: g = l>>4, o = l&15. A-slot j of lane l at ks holds T_{8h+j}(x[row][f]),
// f = 16P + 4g + q  => per P a lane needs ONE float4 of x (cols 16P+4g..+3), and the
// wave's 64 float4 = 16 complete 64B lines. No separate prep dispatch: each block
// converts w into LDS B-fragment layout itself.
//
// LDS w layout, 16B slots s (0..4095): slot for (o,f,h) = (2*(o*128+f) + h) ^ (o&7).
// Element j of slot = (_Float16)w[o][f][8h+j].
// Read side (fixed ks): s%8 = (2q+h) ^ (o&7) -> 8 lanes per bank-group = even spread.

__device__ __forceinline__ void cheb_frags(float xv, f16x8& ae, f16x8& ao) {
    float x2 = xv + xv;
    float t2  = __builtin_fmaf(x2, xv,  -1.0f);
    float t3  = __builtin_fmaf(x2, t2,  -xv);
    float t4  = __builtin_fmaf(x2, t3,  -t2);
    float t5  = __builtin_fmaf(x2, t4,  -t3);
    float t6  = __builtin_fmaf(x2, t5,  -t4);
    float t7  = __builtin_fmaf(x2, t6,  -t5);
    float t8  = __builtin_fmaf(x2, t7,  -t6);
    float t9  = __builtin_fmaf(x2, t8,  -t7);
    float t10 = __builtin_fmaf(x2, t9,  -t8);
    float t11 = __builtin_fmaf(x2, t10, -t9);
    float t12 = __builtin_fmaf(x2, t11, -t10);
    float t13 = __builtin_fmaf(x2, t12, -t11);
    float t14 = __builtin_fmaf(x2, t13, -t12);
    float t15 = __builtin_fmaf(x2, t14, -t13);
    union { f16x8 v; fp16x2 h[4]; } e, od;
    e.h[0]  = __builtin_amdgcn_cvt_pkrtz(1.0f, xv);
    e.h[1]  = __builtin_amdgcn_cvt_pkrtz(t2,  t3);
    e.h[2]  = __builtin_amdgcn_cvt_pkrtz(t4,  t5);
    e.h[3]  = __builtin_amdgcn_cvt_pkrtz(t6,  t7);
    od.h[0] = __builtin_amdgcn_cvt_pkrtz(t8,  t9);
    od.h[1] = __builtin_amdgcn_cvt_pkrtz(t10, t11);
    od.h[2] = __builtin_amdgcn_cvt_pkrtz(t12, t13);
    od.h[3] = __builtin_amdgcn_cvt_pkrtz(t14, t15);
    ae = e.v;
    ao = od.v;
}

// block = 256 threads = 4 waves; wave = 32 rows (2 MFMA row-tiles sharing B-frags);
// grid = 512; 64KB LDS -> 2 blocks/CU.
__global__ __launch_bounds__(256) void cheb_fused(const float* __restrict__ x,
                                                  const float* __restrict__ w,
                                                  float* __restrict__ out) {
    __shared__ _Float16 wlds[32768];           // 64 KB
    const int tid = threadIdx.x;
    const long row0 = (long)blockIdx.x * 128;

    const int l  = tid & 63;
    const int wv = tid >> 6;
    const int g  = l >> 4;
    const int o  = l & 15;
    const int lm = l & 15;

    const long r0 = row0 + wv * 32 + lm;
    const long r1 = r0 + 16;
    const f32x4* x4 = (const f32x4*)x;         // 32 float4 per row

    // issue x loads first so HBM latency hides under the w conversion + barrier
    f32x4 xa[8], xb[8];
    #pragma unroll
    for (int P = 0; P < 8; ++P) {
        xa[P] = x4[r0 * 32 + P * 4 + g];
        xb[P] = x4[r1 * 32 + P * 4 + g];
    }

    // convert w -> LDS fragment layout. thread handles (o,f) pairs p = k*256+tid:
    // 64B coalesced global read per pair, two swizzled 16B LDS writes.
    #pragma unroll
    for (int k = 0; k < 8; ++k) {
        int p = k * 256 + tid;                 // p = o*128 + f
        const float4* src = (const float4*)(w + (size_t)p * 16);
        float4 a = src[0], b = src[1], c = src[2], d = src[3];
        union { f16x8 v; fp16x2 h[4]; } E, O;
        E.h[0] = __builtin_amdgcn_cvt_pkrtz(a.x, a.y);
        E.h[1] = __builtin_amdgcn_cvt_pkrtz(a.z, a.w);
        E.h[2] = __builtin_amdgcn_cvt_pkrtz(b.x, b.y);
        E.h[3] = __builtin_amdgcn_cvt_pkrtz(b.z, b.w);
        O.h[0] = __builtin_amdgcn_cvt_pkrtz(c.x, c.y);
        O.h[1] = __builtin_amdgcn_cvt_pkrtz(c.z, c.w);
        O.h[2] = __builtin_amdgcn_cvt_pkrtz(d.x, d.y);
        O.h[3] = __builtin_amdgcn_cvt_pkrtz(d.z, d.w);
        int s0 = (2 * p) ^ ((p >> 7) & 7);     // ^ (o&7)
        *(f16x8*)&wlds[s0 * 8]       = E.v;
        *(f16x8*)&wlds[(s0 ^ 1) * 8] = O.v;
    }
    __syncthreads();

    f32x4 acc0 = {0.f, 0.f, 0.f, 0.f};
    f32x4 acc1 = {0.f, 0.f, 0.f, 0.f};

    const int Aslot = 256 * o + 8 * g;         // slot = Aslot + 32P + (2q ^ key)
    const int key = o & 7;

    #pragma unroll
    for (int P = 0; P < 8; ++P) {
        #pragma unroll
        for (int q = 0; q < 4; ++q) {
            int s0 = Aslot + 32 * P + ((2 * q) ^ key);
            f16x8 b0 = *(const f16x8*)&wlds[s0 * 8];
            f16x8 b1 = *(const f16x8*)&wlds[(s0 ^ 1) * 8];
            f16x8 a0e, a0o, a1e, a1o;
            cheb_frags(xa[P][q], a0e, a0o);
            cheb_frags(xb[P][q], a1e, a1o);
            acc0 = __builtin_amdgcn_mfma_f32_16x16x32_f16(a0e, b0, acc0, 0, 0, 0);
            acc0 = __builtin_amdgcn_mfma_f32_16x16x32_f16(a0o, b1, acc0, 0, 0, 0);
            acc1 = __builtin_amdgcn_mfma_f32_16x16x32_f16(a1e, b0, acc1, 0, 0, 0);
            acc1 = __builtin_amdgcn_mfma_f32_16x16x32_f16(a1o, b1, acc1, 0, 0, 0);
        }
    }

    // C/D layout: col = lane&15 (=o), row = 4*(lane>>4) + reg
    float* op = out + (row0 + wv * 32 + 4 * g) * OUT_F + o;
    #pragma unroll
    for (int rr = 0; rr < 4; ++rr) {
        op[rr * OUT_F] = acc0[rr];
        op[(16 + rr) * OUT_F] = acc1[rr];
    }
}

extern "C" void kernel_launch(void* const* d_in, const int* in_sizes, int n_in,
                              void* d_out, int out_size, void* d_ws, size_t ws_size,
                              hipStream_t stream) {
    const float* x = (const float*)d_in[0];
    const float* w = (const float*)d_in[1];
    float* out = (float*)d_out;
    cheb_fused<<<512, 256, 0, stream>>>(x, w, out);
}

// Round 6
// 16.767 us; speedup vs baseline: 1.4555x; 1.0663x over previous
//
#include <hip/hip_runtime.h>
#include <hip/hip_bf16.h>

typedef _Float16 f16x8 __attribute__((ext_vector_type(8)));
typedef __fp16  fp16x2 __attribute__((ext_vector_type(2)));
typedef float f32x4 __attribute__((ext_vector_type(4)));

#define IN_F 128
#define OUT_F 16
#define NB 16
// K = 2048 = 64 K-steps of 32. K-step ks = 8P + 2q + h (P=0..7, q=0..3, h=0..1).
// Lane l: g = l>>4, o = l&15. A-slot j of lane l at ks holds T_{8h+j}(x[row][f]),
// f = 16P + 4g + q  => per P a lane needs ONE float4 of x (cols 16P+4g..+3); the
// wave's 64 float4 = 16 complete 64B lines. Single dispatch: each block converts
// w into its LDS B-fragment layout itself.
//
// LDS w layout, 16B slots s (0..4095): slot for (o,f,h) = (2*(o*128+f) + h) ^ (o&7).
// Element j of slot = (_Float16)w[o][f][8h+j].

__device__ __forceinline__ void cheb_frags(float xv, f16x8& ae, f16x8& ao) {
    float x2 = xv + xv;
    float t2  = __builtin_fmaf(x2, xv,  -1.0f);
    float t3  = __builtin_fmaf(x2, t2,  -xv);
    float t4  = __builtin_fmaf(x2, t3,  -t2);
    float t5  = __builtin_fmaf(x2, t4,  -t3);
    float t6  = __builtin_fmaf(x2, t5,  -t4);
    float t7  = __builtin_fmaf(x2, t6,  -t5);
    float t8  = __builtin_fmaf(x2, t7,  -t6);
    float t9  = __builtin_fmaf(x2, t8,  -t7);
    float t10 = __builtin_fmaf(x2, t9,  -t8);
    float t11 = __builtin_fmaf(x2, t10, -t9);
    float t12 = __builtin_fmaf(x2, t11, -t10);
    float t13 = __builtin_fmaf(x2, t12, -t11);
    float t14 = __builtin_fmaf(x2, t13, -t12);
    float t15 = __builtin_fmaf(x2, t14, -t13);
    union { f16x8 v; fp16x2 h[4]; } e, od;
    e.h[0]  = __builtin_amdgcn_cvt_pkrtz(1.0f, xv);
    e.h[1]  = __builtin_amdgcn_cvt_pkrtz(t2,  t3);
    e.h[2]  = __builtin_amdgcn_cvt_pkrtz(t4,  t5);
    e.h[3]  = __builtin_amdgcn_cvt_pkrtz(t6,  t7);
    od.h[0] = __builtin_amdgcn_cvt_pkrtz(t8,  t9);
    od.h[1] = __builtin_amdgcn_cvt_pkrtz(t10, t11);
    od.h[2] = __builtin_amdgcn_cvt_pkrtz(t12, t13);
    od.h[3] = __builtin_amdgcn_cvt_pkrtz(t14, t15);
    ae = e.v;
    ao = od.v;
}

// block = 512 threads = 8 waves; each wave = 16 rows (one MFMA tile, one acc);
// 128 rows/block, grid = 512 -> 2 blocks/CU (128KB LDS/CU), 16 waves/CU = 4/SIMD.
__global__ __launch_bounds__(512, 4) void cheb_fused(const float* __restrict__ x,
                                                     const float* __restrict__ w,
                                                     float* __restrict__ out) {
    __shared__ _Float16 wlds[32768];           // 64 KB
    const int tid = threadIdx.x;
    const long row0 = (long)blockIdx.x * 128;

    const int l  = tid & 63;
    const int wv = tid >> 6;                   // 0..7
    const int g  = l >> 4;
    const int o  = l & 15;
    const int lm = l & 15;

    const long r0 = row0 + wv * 16 + lm;
    const f32x4* x4 = (const f32x4*)x;         // 32 float4 per row

    // issue x loads first so HBM latency hides under the w conversion + barrier
    f32x4 xa[8];
    #pragma unroll
    for (int P = 0; P < 8; ++P) xa[P] = x4[r0 * 32 + P * 4 + g];

    // convert w -> LDS fragment layout: 2048 (o,f) pairs over 512 threads;
    // 64B coalesced global read per pair, two swizzled 16B LDS writes.
    #pragma unroll
    for (int k = 0; k < 4; ++k) {
        int p = k * 512 + tid;                 // p = o*128 + f
        const float4* src = (const float4*)(w + (size_t)p * 16);
        float4 a = src[0], b = src[1], c = src[2], d = src[3];
        union { f16x8 v; fp16x2 h[4]; } E, O;
        E.h[0] = __builtin_amdgcn_cvt_pkrtz(a.x, a.y);
        E.h[1] = __builtin_amdgcn_cvt_pkrtz(a.z, a.w);
        E.h[2] = __builtin_amdgcn_cvt_pkrtz(b.x, b.y);
        E.h[3] = __builtin_amdgcn_cvt_pkrtz(b.z, b.w);
        O.h[0] = __builtin_amdgcn_cvt_pkrtz(c.x, c.y);
        O.h[1] = __builtin_amdgcn_cvt_pkrtz(c.z, c.w);
        O.h[2] = __builtin_amdgcn_cvt_pkrtz(d.x, d.y);
        O.h[3] = __builtin_amdgcn_cvt_pkrtz(d.z, d.w);
        int s0 = (2 * p) ^ ((p >> 7) & 7);     // ^ (o&7)
        *(f16x8*)&wlds[s0 * 8]       = E.v;
        *(f16x8*)&wlds[(s0 ^ 1) * 8] = O.v;
    }
    __syncthreads();

    f32x4 acc = {0.f, 0.f, 0.f, 0.f};

    const int Aslot = 256 * o + 8 * g;         // slot = Aslot + 32P + (2q ^ key)
    const int key = o & 7;

    #pragma unroll
    for (int P = 0; P < 8; ++P) {
        #pragma unroll
        for (int q = 0; q < 4; ++q) {
            int s0 = Aslot + 32 * P + ((2 * q) ^ key);
            f16x8 b0 = *(const f16x8*)&wlds[s0 * 8];
            f16x8 b1 = *(const f16x8*)&wlds[(s0 ^ 1) * 8];
            f16x8 ae, ao;
            cheb_frags(xa[P][q], ae, ao);
            acc = __builtin_amdgcn_mfma_f32_16x16x32_f16(ae, b0, acc, 0, 0, 0);
            acc = __builtin_amdgcn_mfma_f32_16x16x32_f16(ao, b1, acc, 0, 0, 0);
        }
    }

    // C/D layout: col = lane&15 (=o), row = 4*(lane>>4) + reg
    float* op = out + (row0 + wv * 16 + 4 * g) * OUT_F + o;
    #pragma unroll
    for (int rr = 0; rr < 4; ++rr) op[rr * OUT_F] = acc[rr];
}

extern "C" void kernel_launch(void* const* d_in, const int* in_sizes, int n_in,
                              void* d_out, int out_size, void* d_ws, size_t ws_size,
                              hipStream_t stream) {
    const float* x = (const float*)d_in[0];
    const float* w = (const float*)d_in[1];
    float* out = (float*)d_out;
    cheb_fused<<<512, 512, 0, stream>>>(x, w, out);
}

// Round 7
// 16.453 us; speedup vs baseline: 1.4832x; 1.0191x over previous
//
#include <hip/hip_runtime.h>
#include <hip/hip_bf16.h>

typedef _Float16 f16x8 __attribute__((ext_vector_type(8)));
typedef _Float16 hf2   __attribute__((ext_vector_type(2)));
typedef __fp16  fp16x2 __attribute__((ext_vector_type(2)));
typedef float f32x4 __attribute__((ext_vector_type(4)));

#define IN_F 128
#define OUT_F 16
#define NB 16
// K = 2048 = 64 K-steps of 32. K-step ks = 8P + 2q + h (P=0..7, q=0..3, h=0..1).
// Lane l: g = l>>4, o = l&15. A-slot j of lane l at ks holds T_{8h+j}(x[row][f]),
// f = 16P + 4g + q. One float4 of x per lane per P; wave = 16 full 64B lines.
// Single dispatch: each block converts w into its LDS B-fragment layout itself.
// LDS w layout, 16B slots s (0..4095): slot for (o,f,h) = (2*(o*128+f) + h) ^ (o&7).

// Packed Chebyshev: pairs h[j] = (T_2j, T_2j+1) satisfy h[j+1] = u*h[j] - h[j-1]
// with u = 2*T2 = 4x^2-2 (from T_{k+2} = 2*T2*T_k - T_{k-2}) -> even/odd chains
// independent, computed 2-at-a-time in v_pk_fma_f16; pair layout IS the A-frag layout.
__device__ __forceinline__ void cheb_frags(float xv, f16x8& ae, f16x8& ao) {
    float T2 = __builtin_fmaf(xv + xv, xv, -1.0f);
    float T3 = __builtin_fmaf(xv + xv, T2, -xv);
    float u  = T2 + T2;
    hf2 h0 = __builtin_bit_cast(hf2, __builtin_amdgcn_cvt_pkrtz(1.0f, xv));
    hf2 h1 = __builtin_bit_cast(hf2, __builtin_amdgcn_cvt_pkrtz(T2, T3));
    hf2 uu = __builtin_bit_cast(hf2, __builtin_amdgcn_cvt_pkrtz(u, u));
    hf2 h2 = __builtin_elementwise_fma(uu, h1, -h0);
    hf2 h3 = __builtin_elementwise_fma(uu, h2, -h1);
    hf2 h4 = __builtin_elementwise_fma(uu, h3, -h2);
    hf2 h5 = __builtin_elementwise_fma(uu, h4, -h3);
    hf2 h6 = __builtin_elementwise_fma(uu, h5, -h4);
    hf2 h7 = __builtin_elementwise_fma(uu, h6, -h5);
    union { f16x8 v; hf2 h[4]; } e, od;
    e.h[0] = h0;  e.h[1] = h1;  e.h[2] = h2;  e.h[3] = h3;
    od.h[0] = h4; od.h[1] = h5; od.h[2] = h6; od.h[3] = h7;
    ae = e.v;
    ao = od.v;
}

// block = 512 threads = 8 waves; each wave = 16 rows (one MFMA tile, one acc);
// 128 rows/block, grid = 512 -> 2 blocks/CU (128KB LDS/CU), 16 waves/CU = 4/SIMD.
__global__ __launch_bounds__(512, 4) void cheb_fused(const float* __restrict__ x,
                                                     const float* __restrict__ w,
                                                     float* __restrict__ out) {
    __shared__ _Float16 wlds[32768];           // 64 KB
    const int tid = threadIdx.x;
    const long row0 = (long)blockIdx.x * 128;

    const int l  = tid & 63;
    const int wv = tid >> 6;                   // 0..7
    const int g  = l >> 4;
    const int o  = l & 15;
    const int lm = l & 15;

    const long r0 = row0 + wv * 16 + lm;
    const f32x4* x4 = (const f32x4*)x;         // 32 float4 per row

    // issue x loads first so HBM latency hides under the w conversion + barrier
    f32x4 xa[8];
    #pragma unroll
    for (int P = 0; P < 8; ++P) xa[P] = x4[r0 * 32 + P * 4 + g];

    // convert w -> LDS fragment layout: 2048 (o,f) pairs over 512 threads;
    // 64B coalesced global read per pair, two swizzled 16B LDS writes.
    #pragma unroll
    for (int k = 0; k < 4; ++k) {
        int p = k * 512 + tid;                 // p = o*128 + f
        const float4* src = (const float4*)(w + (size_t)p * 16);
        float4 a = src[0], b = src[1], c = src[2], d = src[3];
        union { f16x8 v; fp16x2 h[4]; } E, O;
        E.h[0] = __builtin_amdgcn_cvt_pkrtz(a.x, a.y);
        E.h[1] = __builtin_amdgcn_cvt_pkrtz(a.z, a.w);
        E.h[2] = __builtin_amdgcn_cvt_pkrtz(b.x, b.y);
        E.h[3] = __builtin_amdgcn_cvt_pkrtz(b.z, b.w);
        O.h[0] = __builtin_amdgcn_cvt_pkrtz(c.x, c.y);
        O.h[1] = __builtin_amdgcn_cvt_pkrtz(c.z, c.w);
        O.h[2] = __builtin_amdgcn_cvt_pkrtz(d.x, d.y);
        O.h[3] = __builtin_amdgcn_cvt_pkrtz(d.z, d.w);
        int s0 = (2 * p) ^ ((p >> 7) & 7);     // ^ (o&7)
        *(f16x8*)&wlds[s0 * 8]       = E.v;
        *(f16x8*)&wlds[(s0 ^ 1) * 8] = O.v;
    }
    __syncthreads();

    f32x4 acc = {0.f, 0.f, 0.f, 0.f};

    const int Aslot = 256 * o + 8 * g;         // slot = Aslot + 32P + (2q ^ key)
    const int key = o & 7;

    #pragma unroll
    for (int P = 0; P < 8; ++P) {
        #pragma unroll
        for (int q = 0; q < 4; ++q) {
            int s0 = Aslot + 32 * P + ((2 * q) ^ key);
            f16x8 b0 = *(const f16x8*)&wlds[s0 * 8];
            f16x8 b1 = *(const f16x8*)&wlds[(s0 ^ 1) * 8];
            f16x8 ae, ao;
            cheb_frags(xa[P][q], ae, ao);
            acc = __builtin_amdgcn_mfma_f32_16x16x32_f16(ae, b0, acc, 0, 0, 0);
            acc = __builtin_amdgcn_mfma_f32_16x16x32_f16(ao, b1, acc, 0, 0, 0);
        }
    }

    // C/D layout: col = lane&15 (=o), row = 4*(lane>>4) + reg
    float* op = out + (row0 + wv * 16 + 4 * g) * OUT_F + o;
    #pragma unroll
    for (int rr = 0; rr < 4; ++rr) op[rr * OUT_F] = acc[rr];
}

extern "C" void kernel_launch(void* const* d_in, const int* in_sizes, int n_in,
                              void* d_out, int out_size, void* d_ws, size_t ws_size,
                              hipStream_t stream) {
    const float* x = (const float*)d_in[0];
    const float* w = (const float*)d_in[1];
    float* out = (float*)d_out;
    cheb_fused<<<512, 512, 0, stream>>>(x, w, out);
}